// Round 10
// baseline (942.575 us; speedup 1.0000x reference)
//
#include <hip/hip_runtime.h>

#define N_ROWS 131072
#define DIM    128
#define QST    4
#define KC     1024
#define BM     128     // rows per workgroup (2 waves x 64 rows)
#define NTH    128
#define PNTH   256
#define NCHUNK 64      // 16 codes per chunk, 8 KB fragments
#define EPS    6e-3f   // certified fp16-split argmin margin
#define FLAGB  (1 << 16)

typedef _Float16 h8  __attribute__((ext_vector_type(8)));
typedef float    fx4 __attribute__((ext_vector_type(4)));

typedef __attribute__((address_space(3))) void lds_void;
typedef const __attribute__((address_space(1))) void glb_void;

#define MFMA16(a, b, c) __builtin_amdgcn_mfma_f32_16x16x32_f16((a), (b), (c), 0, 0, 0)

// packB halfs layout: [q][ch(64)][kt(4)][hl(2)][lane(64)][j(8)]
// -> each 8 KB chunk (16 codes) stages linearly into LDS.
__global__ void k_prep(const float* __restrict__ cb,
                       double* __restrict__ cvec64, float* __restrict__ cvec32,
                       _Float16* __restrict__ packB) {
  int gid = blockIdx.x * blockDim.x + threadIdx.x;
  if (gid >= QST * KC) return;
  int q = gid >> 10, code = gid & (KC - 1);
  int ch = code >> 4, n = code & 15;
  const float* e = cb + ((size_t)q * KC + code) * DIM;
  double s = 0.0;
  for (int d = 0; d < DIM; d++) {
    float v = e[d];
    s = fma((double)v, (double)v, s);
    int kt = d >> 5, g = (d >> 3) & 3, j = d & 7;
    int lane = g * 16 + n;
    size_t base = ((size_t)q * NCHUNK + ch) * 4096 + (size_t)kt * 1024 + lane * 8 + j;
    _Float16 hh = (_Float16)v;
    packB[base]       = hh;                          // hi
    packB[base + 512] = (_Float16)(v - (float)hh);   // lo
  }
  cvec64[q * KC + code] = s;
  cvec32[q * KC + code] = (float)s;
}

__global__ __launch_bounds__(NTH, 2) void k_stage(
    int st, const float* rin, float* rout, const float* __restrict__ x,
    const float* __restrict__ cb,
    const double* __restrict__ cvec64, const float* __restrict__ cvec32,
    const _Float16* __restrict__ packB,
    float* __restrict__ oidx, float* __restrict__ lpart, int final_stage)
{
  extern __shared__ float smem[];
  _Float16* Bl    = (_Float16*)smem;              // [2 waves][2 bufs][4096 halfs] = 32 KB
  float*    cvecL = smem + 8192;                  // 1024 floats = 4 KB
  int*      idxs  = (int*)(smem + 9216);          // 128 ints
  double*   redd  = (double*)(smem + 9344);       // 2 doubles (8B aligned)
  int*      redi  = (int*)(smem + 9348);          // 2 ints
  float*    redf  = smem + 9350;                  // 2 floats
  int*      flags = (int*)(smem + 9352);          // 2 ints

  const int tid = threadIdx.x;
  const int lane = tid & 63, wv = tid >> 6;       // wv in {0,1}
  const int tx = lane & 15;
  const size_t rowbase = (size_t)blockIdx.x * BM;

  const double*   cq64 = cvec64 + st * KC;
  const float*    cq32 = cvec32 + st * KC;
  const float*    Eq   = cb + (size_t)st * KC * DIM;
  const _Float16* PBq  = packB + (size_t)st * 262144;

  // ---- stage cvec32 into LDS (main-loop score reads must not touch vmcnt)
  for (int i = tid; i < KC; i += NTH) cvecL[i] = cq32[i];

  // ---- A-fragments: 4 rowtiles x 4 ktiles, fp16 hi/lo, straight from global
  h8 ah[4][4], al[4][4];
  #pragma unroll
  for (int rt = 0; rt < 4; rt++) {
    const float* rowp = rin + (rowbase + wv * 64 + rt * 16 + (lane & 15)) * (size_t)DIM
                        + ((lane >> 4) * 8);
    #pragma unroll
    for (int kt = 0; kt < 4; kt++) {
      float4 f0 = *(const float4*)(rowp + kt * 32);
      float4 f1 = *(const float4*)(rowp + kt * 32 + 4);
      float vv[8] = {f0.x, f0.y, f0.z, f0.w, f1.x, f1.y, f1.z, f1.w};
      #pragma unroll
      for (int j = 0; j < 8; j++) {
        _Float16 hh = (_Float16)vv[j];
        ah[rt][kt][j] = hh;
        al[rt][kt][j] = (_Float16)(vv[j] - (float)hh);
      }
    }
  }

  __syncthreads();   // cvecL visible; also drains all prologue VMEM (vmcnt->0)

  // wave-private ring-2; stage one 8 KB chunk: 8 x (64 lanes x 16 B)
  _Float16* myB = Bl + wv * 8192;
  auto stageB = [&](int ch, int buf) {
    const _Float16* src = PBq + (size_t)ch * 4096 + lane * 8;
    _Float16* dst = myB + buf * 4096;   // wave-uniform base
    #pragma unroll
    for (int i = 0; i < 8; i++)
      __builtin_amdgcn_global_load_lds((glb_void*)(src + i * 512),
                                       (lds_void*)(dst + i * 512), 16, 0, 0);
  };

  float b1[16], b2[16];
  int   i1[16];
  #pragma unroll
  for (int i = 0; i < 16; i++) { b1[i] = 3.4e38f; b2[i] = 3.4e38f; i1[i] = 0; }

  const fx4 zero4 = {0.f, 0.f, 0.f, 0.f};

  // prologue: fill ring (16 loads in flight, wave-private counting)
  stageB(0, 0); stageB(1, 1);

  #pragma unroll 1
  for (int ch = 0; ch < NCHUNK; ch++) {
    // counted per-wave wait (T4): stage(ch) retired; stage(ch+1) stays in flight
    if (ch < NCHUNK - 1) asm volatile("s_waitcnt vmcnt(8)" ::: "memory");
    else                 asm volatile("s_waitcnt vmcnt(0)" ::: "memory");

    const _Float16* Bb = myB + (ch & 1) * 4096;
    fx4 acc[4];
    acc[0] = zero4; acc[1] = zero4; acc[2] = zero4; acc[3] = zero4;

    __builtin_amdgcn_s_setprio(1);
    #pragma unroll
    for (int kt = 0; kt < 4; kt++) {
      const _Float16* p = Bb + (size_t)kt * 1024 + lane * 8;
      h8 bh = *(const h8*)p;
      h8 bl = *(const h8*)(p + 512);
      #pragma unroll
      for (int rt = 0; rt < 4; rt++) {
        acc[rt] = MFMA16(ah[rt][kt], bh, acc[rt]);
        acc[rt] = MFMA16(al[rt][kt], bh, acc[rt]);
        acc[rt] = MFMA16(ah[rt][kt], bl, acc[rt]);
      }
    }
    __builtin_amdgcn_s_setprio(0);

    // all this chunk's ds_reads are in registers -> WAR-safe to overwrite buffer
    asm volatile("s_waitcnt lgkmcnt(0)" ::: "memory");
    if (ch + 2 < NCHUNK) stageB(ch + 2, ch & 1);

    // ---- scores; per-row top-2. C layout: col=lane&15, row=(lane>>4)*4+reg
    {
      int code = ch * 16 + tx;
      float cvv = cvecL[code];
      #pragma unroll
      for (int rt = 0; rt < 4; rt++) {
        #pragma unroll
        for (int j = 0; j < 4; j++) {
          float sc = fmaf(-2.f, acc[rt][j], cvv);
          int r = rt * 4 + j;
          if (sc < b1[r]) { b2[r] = b1[r]; b1[r] = sc; i1[r] = code; }
          else            { b2[r] = fminf(b2[r], sc); }
        }
      }
    }
  }

  // ---- cross-lane top-2 reduce over the 16 lanes sharing each row
  #pragma unroll
  for (int m = 1; m < 16; m <<= 1) {
    #pragma unroll
    for (int r = 0; r < 16; r++) {
      float ob1 = __shfl_xor(b1[r], m, 64);
      int   oi1 = __shfl_xor(i1[r], m, 64);
      float ob2 = __shfl_xor(b2[r], m, 64);
      bool take = (ob1 < b1[r]) || (ob1 == b1[r] && oi1 < i1[r]);
      float loser = take ? b1[r] : ob1;
      if (take) { b1[r] = ob1; i1[r] = oi1; }
      b2[r] = fminf(fminf(b2[r], ob2), loser);
    }
  }

  if (tx == 0) {
    int g = lane >> 4;
    #pragma unroll
    for (int rt = 0; rt < 4; rt++)
      #pragma unroll
      for (int j = 0; j < 4; j++) {
        int r = rt * 4 + j;
        int fl = (b2[r] - b1[r] <= EPS) ? FLAGB : 0;
        idxs[wv * 64 + rt * 16 + g * 4 + j] = i1[r] | fl;
      }
  }
  __syncthreads();

  // ---- exact fp64 rescue for uncertain rows (rare); reads codebook rows
  {
    bool pred = (idxs[tid] & FLAGB) != 0;
    unsigned long long bal = __ballot(pred);
    if (lane == 0) flags[wv] = (bal != 0ull) ? 1 : 0;
  }
  __syncthreads();
  int anyflag = flags[0] | flags[1];
  if (anyflag) {
    for (int row = 0; row < BM; row++) {
      if (!(idxs[row] & FLAGB)) continue;          // uniform branch
      const float* rrow = rin + (rowbase + row) * (size_t)DIM;
      double dot[8] = {0.0, 0.0, 0.0, 0.0, 0.0, 0.0, 0.0, 0.0};
      for (int d = 0; d < DIM; d++) {
        double a = (double)rrow[d];                // broadcast load
        #pragma unroll
        for (int c = 0; c < 8; c++)
          dot[c] = fma(a, (double)Eq[(size_t)(tid + c * NTH) * DIM + d], dot[c]);
      }
      double bs = 1e300; int bk = 0;
      #pragma unroll
      for (int c = 0; c < 8; c++) {
        int k = tid + c * NTH;
        double s = fma(-2.0, dot[c], cq64[k]);
        if (s < bs || (s == bs && k < bk)) { bs = s; bk = k; }
      }
      #pragma unroll
      for (int m = 1; m < 64; m <<= 1) {
        double ob = __shfl_xor(bs, m, 64);
        int    ok = __shfl_xor(bk, m, 64);
        if (ob < bs || (ob == bs && ok < bk)) { bs = ob; bk = ok; }
      }
      if (lane == 0) { redd[wv] = bs; redi[wv] = bk; }
      __syncthreads();
      if (tid == 0) {
        double fb = redd[0]; int fk = redi[0];
        if (redd[1] < fb || (redd[1] == fb && redi[1] < fk)) { fb = redd[1]; fk = redi[1]; }
        idxs[row] = fk;                            // flag cleared
      }
      __syncthreads();
    }
  }

  // ---- fused epilogue, fully coalesced flat writes:
  //      r_new = r_old - E[idx]; loss += (E[idx]-r_old)^2; last stage: out = x - r_new
  {
    float lsum = 0.f;
    #pragma unroll 1
    for (int it = 0; it < 32; it++) {
      int g = it * NTH + tid;
      int row = g >> 5, c4 = g & 31;
      int kidx = idxs[row] & 1023;
      if ((g & 31) == 0) oidx[(rowbase + row) * 4 + st] = (float)kidx;
      float4 ev = *(const float4*)(Eq + (size_t)kidx * DIM + c4 * 4);
      float4 rv = *(const float4*)(rin + (rowbase + row) * (size_t)DIM + c4 * 4);
      float4 dv = make_float4(rv.x - ev.x, rv.y - ev.y, rv.z - ev.z, rv.w - ev.w);
      lsum = fmaf(dv.x, dv.x, lsum);
      lsum = fmaf(dv.y, dv.y, lsum);
      lsum = fmaf(dv.z, dv.z, lsum);
      lsum = fmaf(dv.w, dv.w, lsum);
      float4 wv4 = dv;
      if (final_stage) {
        float4 xv = *(const float4*)(x + (rowbase + row) * (size_t)DIM + c4 * 4);
        wv4 = make_float4(xv.x - dv.x, xv.y - dv.y, xv.z - dv.z, xv.w - dv.w);
      }
      *(float4*)(rout + (rowbase + row) * (size_t)DIM + c4 * 4) = wv4;
    }
    #pragma unroll
    for (int m = 1; m < 64; m <<= 1) lsum += __shfl_xor(lsum, m, 64);
    if (lane == 0) redf[wv] = lsum;
    __syncthreads();
    if (tid == 0) lpart[st * (N_ROWS / BM) + blockIdx.x] = redf[0] + redf[1];
  }
}

__global__ void k_loss(const float* __restrict__ part, float* __restrict__ o) {
  __shared__ float red[4];
  int tid = threadIdx.x;
  float s = 0.f;
  for (int i = tid; i < QST * (N_ROWS / BM); i += PNTH) s += part[i];
  #pragma unroll
  for (int m = 1; m < 64; m <<= 1) s += __shfl_xor(s, m, 64);
  if ((tid & 63) == 0) red[tid >> 6] = s;
  __syncthreads();
  if (tid == 0)
    o[0] = (red[0] + red[1] + red[2] + red[3]) *
           (1.25f / ((float)QST * (float)N_ROWS * (float)DIM));
}

extern "C" void kernel_launch(void* const* d_in, const int* in_sizes, int n_in,
                              void* d_out, int out_size, void* d_ws, size_t ws_size,
                              hipStream_t stream) {
  const float* x  = (const float*)d_in[0];
  const float* cb = (const float*)d_in[1];
  float* out = (float*)d_out;
  float* ws  = (float*)d_ws;

  float*    r      = out;                                   // residual in x_q region
  double*   cvec64 = (double*)ws;                           // Q*K fp64 ||E||^2
  float*    cvec32 = (float*)(cvec64 + (size_t)QST * KC);
  float*    part   = cvec32 + (size_t)QST * KC;             // Q*1024 partials
  _Float16* packB  = (_Float16*)(part + (size_t)QST * (N_ROWS / BM)); // 2 MB frags

  float* out_loss = out + (size_t)N_ROWS * DIM;
  float* out_idx  = out_loss + 1;

  static const size_t SMEM = 9354 * sizeof(float); // 37416 B -> exactly 4 blocks/CU
  hipFuncSetAttribute(reinterpret_cast<const void*>(k_stage),
                      hipFuncAttributeMaxDynamicSharedMemorySize, (int)SMEM);

  k_prep<<<(QST * KC + PNTH - 1) / PNTH, PNTH, 0, stream>>>(cb, cvec64, cvec32, packB);

  for (int s = 0; s < QST; s++) {
    const float* rin = (s == 0) ? x : r;
    k_stage<<<N_ROWS / BM, NTH, SMEM, stream>>>(s, rin, r, x, cb, cvec64, cvec32,
                                                packB, out_idx, part,
                                                (s == QST - 1) ? 1 : 0);
  }

  k_loss<<<1, PNTH, 0, stream>>>(part, out_loss);
}

// Round 11
// 735.713 us; speedup vs baseline: 1.2812x; 1.2812x over previous
//
#include <hip/hip_runtime.h>

#define N_ROWS 131072
#define DIM    128
#define QST    4
#define KC     1024
#define BM     128     // rows per workgroup (4 waves x 32 rows)
#define NTH    256
#define PNTH   256
#define NWAVE  4
#define NCHUNK 64      // 16 codes per chunk, 8 KB fragments
#define NPAIR  32
#define EPS    6e-3f   // certified fp16-split argmin margin
#define FLAGB  (1 << 16)

typedef _Float16 h8  __attribute__((ext_vector_type(8)));
typedef float    fx4 __attribute__((ext_vector_type(4)));

typedef __attribute__((address_space(3))) void lds_void;
typedef const __attribute__((address_space(1))) void glb_void;

#define MFMA16(a, b, c) __builtin_amdgcn_mfma_f32_16x16x32_f16((a), (b), (c), 0, 0, 0)

// packB halfs layout: [q][ch(64)][kt(4)][hl(2)][lane(64)][j(8)]
// -> each 8 KB chunk (16 codes) stages linearly into LDS.
__global__ void k_prep(const float* __restrict__ cb,
                       double* __restrict__ cvec64, float* __restrict__ cvec32,
                       _Float16* __restrict__ packB) {
  int gid = blockIdx.x * blockDim.x + threadIdx.x;
  if (gid >= QST * KC) return;
  int q = gid >> 10, code = gid & (KC - 1);
  int ch = code >> 4, n = code & 15;
  const float* e = cb + ((size_t)q * KC + code) * DIM;
  double s = 0.0;
  for (int d = 0; d < DIM; d++) {
    float v = e[d];
    s = fma((double)v, (double)v, s);
    int kt = d >> 5, g = (d >> 3) & 3, j = d & 7;
    int lane = g * 16 + n;
    size_t base = ((size_t)q * NCHUNK + ch) * 4096 + (size_t)kt * 1024 + lane * 8 + j;
    _Float16 hh = (_Float16)v;
    packB[base]       = hh;                          // hi
    packB[base + 512] = (_Float16)(v - (float)hh);   // lo
  }
  cvec64[q * KC + code] = s;
  cvec32[q * KC + code] = (float)s;
}

__global__ __launch_bounds__(NTH, 2) void k_stage(
    int st, const float* rin, float* rout, const float* __restrict__ x,
    const float* __restrict__ cb,
    const double* __restrict__ cvec64, const float* __restrict__ cvec32,
    const _Float16* __restrict__ packB,
    float* __restrict__ oidx, float* __restrict__ lpart, int final_stage)
{
  extern __shared__ float smem[];
  _Float16* Bl    = (_Float16*)smem;              // [8][4096] halfs = 64 KB ring
  float*    cvecL = smem + 16384;                 // 1024 floats = 4 KB
  int*      idxs  = (int*)(smem + 17408);         // 128 ints
  double*   redd  = (double*)(smem + 17536);      // 4 doubles (8B aligned)
  int*      redi  = (int*)(smem + 17544);         // 4 ints
  float*    redf  = smem + 17548;                 // 4 floats
  int*      flags = (int*)(smem + 17552);         // 4 ints

  const int tid = threadIdx.x;
  const int lane = tid & 63, wv = tid >> 6;
  const int tx = lane & 15;
  const size_t rowbase = (size_t)blockIdx.x * BM;

  const double*   cq64 = cvec64 + st * KC;
  const float*    cq32 = cvec32 + st * KC;
  const float*    Eq   = cb + (size_t)st * KC * DIM;
  const _Float16* PBq  = packB + (size_t)st * 262144;

  // ---- stage cvec32 into LDS (main-loop score reads must not touch vmcnt)
  for (int i = tid; i < KC; i += NTH) cvecL[i] = cq32[i];

  // ---- A-fragments: 2 rowtiles x 4 ktiles, fp16 hi/lo, straight from global
  h8 ah[2][4], al[2][4];
  #pragma unroll
  for (int rt = 0; rt < 2; rt++) {
    const float* rowp = rin + (rowbase + wv * 32 + rt * 16 + (lane & 15)) * (size_t)DIM
                        + ((lane >> 4) * 8);
    #pragma unroll
    for (int kt = 0; kt < 4; kt++) {
      float4 f0 = *(const float4*)(rowp + kt * 32);
      float4 f1 = *(const float4*)(rowp + kt * 32 + 4);
      float vv[8] = {f0.x, f0.y, f0.z, f0.w, f1.x, f1.y, f1.z, f1.w};
      #pragma unroll
      for (int j = 0; j < 8; j++) {
        _Float16 hh = (_Float16)vv[j];
        ah[rt][kt][j] = hh;
        al[rt][kt][j] = (_Float16)(vv[j] - (float)hh);
      }
    }
  }

  __syncthreads();   // cvecL visible; drains all prologue VMEM (vmcnt->0)

  // stage one 8 KB chunk into ring buf (c&7): per wave 2 x (64 lanes x 16 B)
  auto stageC = [&](int c) {
    const _Float16* src = PBq + (size_t)c * 4096 + wv * 1024 + lane * 8;
    _Float16* dst = Bl + (size_t)(c & 7) * 4096 + wv * 1024;   // wave-uniform base
    #pragma unroll
    for (int i = 0; i < 2; i++)
      __builtin_amdgcn_global_load_lds((glb_void*)(src + i * 512),
                                       (lds_void*)(dst + i * 512), 16, 0, 0);
  };

  float b1[8], b2[8];
  int   i1[8];
  #pragma unroll
  for (int i = 0; i < 8; i++) { b1[i] = 3.4e38f; b2[i] = 3.4e38f; i1[i] = 0; }

  const fx4 zero4 = {0.f, 0.f, 0.f, 0.f};

  // prologue: 3 pairs in flight (12 loads/wave)
  stageC(0); stageC(1); stageC(2); stageC(3); stageC(4); stageC(5);

  #pragma unroll 1
  for (int ip = 0; ip < NPAIR; ip++) {
    // counted wait (T4): pair ip's 4 loads retired; pairs ip+1, ip+2 in flight
    if (ip < NPAIR - 2)       asm volatile("s_waitcnt vmcnt(8)" ::: "memory");
    else if (ip == NPAIR - 2) asm volatile("s_waitcnt vmcnt(4)" ::: "memory");
    else                      asm volatile("s_waitcnt vmcnt(0)" ::: "memory");
    __builtin_amdgcn_s_barrier();   // all waves' pair-ip loads landed; pair ip-1 retired
    asm volatile("" ::: "memory");  // pin the stage below the barrier
    if (ip + 3 < NPAIR) { stageC(2 * (ip + 3)); stageC(2 * (ip + 3) + 1); }
    // ledger: stage writes bufs (2ip+6)&7,(2ip+7)&7 == pair ip-1's bufs (consumed,
    // barrier-retired); current pair reads (2ip)&7,(2ip+1)&7; in-flight pairs
    // ip+1,ip+2 occupy (2ip+2..2ip+5)&7 -> disjoint.

    // ---- MFMA: two 16-code groups, 2-acc split (chains depth 8 and 4)
    fx4 acch[2][2], accl[2][2];
    #pragma unroll
    for (int g = 0; g < 2; g++)
      #pragma unroll
      for (int rt = 0; rt < 2; rt++) { acch[g][rt] = zero4; accl[g][rt] = zero4; }

    __builtin_amdgcn_s_setprio(1);
    #pragma unroll
    for (int g = 0; g < 2; g++) {
      int c = 2 * ip + g;
      const _Float16* Bb = Bl + (size_t)(c & 7) * 4096;
      #pragma unroll
      for (int kt = 0; kt < 4; kt++) {
        const _Float16* p = Bb + kt * 1024 + lane * 8;
        h8 bh = *(const h8*)p;
        h8 bl = *(const h8*)(p + 512);
        #pragma unroll
        for (int rt = 0; rt < 2; rt++) {
          acch[g][rt] = MFMA16(ah[rt][kt], bh, acch[g][rt]);
          acch[g][rt] = MFMA16(al[rt][kt], bh, acch[g][rt]);
          accl[g][rt] = MFMA16(ah[rt][kt], bl, accl[g][rt]);
        }
      }
    }
    __builtin_amdgcn_s_setprio(0);

    // ---- scores (G0 overlaps G1's MFMA drain); per-row top-2
    #pragma unroll
    for (int g = 0; g < 2; g++) {
      int code = (2 * ip + g) * 16 + tx;
      float cvv = cvecL[code];
      #pragma unroll
      for (int rt = 0; rt < 2; rt++) {
        #pragma unroll
        for (int j = 0; j < 4; j++) {
          float s = acch[g][rt][j] + accl[g][rt][j];
          float sc = fmaf(-2.f, s, cvv);
          int r = rt * 4 + j;
          if (sc < b1[r]) { b2[r] = b1[r]; b1[r] = sc; i1[r] = code; }
          else            { b2[r] = fminf(b2[r], sc); }
        }
      }
    }
  }

  // ---- cross-lane top-2 reduce over the 16 lanes sharing each row
  #pragma unroll
  for (int m = 1; m < 16; m <<= 1) {
    #pragma unroll
    for (int r = 0; r < 8; r++) {
      float ob1 = __shfl_xor(b1[r], m, 64);
      int   oi1 = __shfl_xor(i1[r], m, 64);
      float ob2 = __shfl_xor(b2[r], m, 64);
      bool take = (ob1 < b1[r]) || (ob1 == b1[r] && oi1 < i1[r]);
      float loser = take ? b1[r] : ob1;
      if (take) { b1[r] = ob1; i1[r] = oi1; }
      b2[r] = fminf(fminf(b2[r], ob2), loser);
    }
  }

  if (tx == 0) {
    int g = lane >> 4;
    #pragma unroll
    for (int rt = 0; rt < 2; rt++)
      #pragma unroll
      for (int j = 0; j < 4; j++) {
        int r = rt * 4 + j;
        int fl = (b2[r] - b1[r] <= EPS) ? FLAGB : 0;
        idxs[wv * 32 + rt * 16 + g * 4 + j] = i1[r] | fl;
      }
  }
  __syncthreads();

  // ---- exact fp64 rescue for uncertain rows (rare); reads codebook rows
  {
    bool pred = (tid < BM) && (idxs[tid] & FLAGB);
    unsigned long long bal = __ballot(pred);
    if (lane == 0) flags[wv] = (bal != 0ull) ? 1 : 0;
  }
  __syncthreads();
  int anyflag = flags[0] | flags[1] | flags[2] | flags[3];
  if (anyflag) {
    for (int row = 0; row < BM; row++) {
      if (!(idxs[row] & FLAGB)) continue;          // uniform branch
      const float* rrow = rin + (rowbase + row) * (size_t)DIM;
      double dot[4] = {0.0, 0.0, 0.0, 0.0};
      for (int d = 0; d < DIM; d++) {
        double a = (double)rrow[d];                // broadcast load
        #pragma unroll
        for (int c = 0; c < 4; c++)
          dot[c] = fma(a, (double)Eq[(size_t)(tid + c * NTH) * DIM + d], dot[c]);
      }
      double bs = 1e300; int bk = 0;
      #pragma unroll
      for (int c = 0; c < 4; c++) {
        int k = tid + c * NTH;
        double s = fma(-2.0, dot[c], cq64[k]);
        if (s < bs || (s == bs && k < bk)) { bs = s; bk = k; }
      }
      #pragma unroll
      for (int m = 1; m < 64; m <<= 1) {
        double ob = __shfl_xor(bs, m, 64);
        int    ok = __shfl_xor(bk, m, 64);
        if (ob < bs || (ob == bs && ok < bk)) { bs = ob; bk = ok; }
      }
      if (lane == 0) { redd[wv] = bs; redi[wv] = bk; }
      __syncthreads();
      if (tid == 0) {
        double fb = redd[0]; int fk = redi[0];
        #pragma unroll
        for (int w = 1; w < NWAVE; w++) {
          if (redd[w] < fb || (redd[w] == fb && redi[w] < fk)) { fb = redd[w]; fk = redi[w]; }
        }
        idxs[row] = fk;                            // flag cleared
      }
      __syncthreads();
    }
  }

  // ---- fused epilogue, fully coalesced flat writes:
  //      r_new = r_old - E[idx]; loss += (E[idx]-r_old)^2; last stage: out = x - r_new
  {
    float lsum = 0.f;
    #pragma unroll 1
    for (int it = 0; it < 16; it++) {
      int g = it * NTH + tid;
      int row = g >> 5, c4 = g & 31;
      int kidx = idxs[row] & 1023;
      if ((g & 31) == 0) oidx[(rowbase + row) * 4 + st] = (float)kidx;
      float4 ev = *(const float4*)(Eq + (size_t)kidx * DIM + c4 * 4);
      float4 rv = *(const float4*)(rin + (rowbase + row) * (size_t)DIM + c4 * 4);
      float4 dv = make_float4(rv.x - ev.x, rv.y - ev.y, rv.z - ev.z, rv.w - ev.w);
      lsum = fmaf(dv.x, dv.x, lsum);
      lsum = fmaf(dv.y, dv.y, lsum);
      lsum = fmaf(dv.z, dv.z, lsum);
      lsum = fmaf(dv.w, dv.w, lsum);
      float4 wv4 = dv;
      if (final_stage) {
        float4 xv = *(const float4*)(x + (rowbase + row) * (size_t)DIM + c4 * 4);
        wv4 = make_float4(xv.x - dv.x, xv.y - dv.y, xv.z - dv.z, xv.w - dv.w);
      }
      *(float4*)(rout + (rowbase + row) * (size_t)DIM + c4 * 4) = wv4;
    }
    #pragma unroll
    for (int m = 1; m < 64; m <<= 1) lsum += __shfl_xor(lsum, m, 64);
    if (lane == 0) redf[wv] = lsum;
    __syncthreads();
    if (tid == 0) lpart[st * (N_ROWS / BM) + blockIdx.x] =
        redf[0] + redf[1] + redf[2] + redf[3];
  }
}

__global__ void k_loss(const float* __restrict__ part, float* __restrict__ o) {
  __shared__ float red[4];
  int tid = threadIdx.x;
  float s = 0.f;
  for (int i = tid; i < QST * (N_ROWS / BM); i += PNTH) s += part[i];
  #pragma unroll
  for (int m = 1; m < 64; m <<= 1) s += __shfl_xor(s, m, 64);
  if ((tid & 63) == 0) red[tid >> 6] = s;
  __syncthreads();
  if (tid == 0)
    o[0] = (red[0] + red[1] + red[2] + red[3]) *
           (1.25f / ((float)QST * (float)N_ROWS * (float)DIM));
}

extern "C" void kernel_launch(void* const* d_in, const int* in_sizes, int n_in,
                              void* d_out, int out_size, void* d_ws, size_t ws_size,
                              hipStream_t stream) {
  const float* x  = (const float*)d_in[0];
  const float* cb = (const float*)d_in[1];
  float* out = (float*)d_out;
  float* ws  = (float*)d_ws;

  float*    r      = out;                                   // residual in x_q region
  double*   cvec64 = (double*)ws;                           // Q*K fp64 ||E||^2
  float*    cvec32 = (float*)(cvec64 + (size_t)QST * KC);
  float*    part   = cvec32 + (size_t)QST * KC;             // Q*1024 partials
  _Float16* packB  = (_Float16*)(part + (size_t)QST * (N_ROWS / BM)); // 2 MB frags

  float* out_loss = out + (size_t)N_ROWS * DIM;
  float* out_idx  = out_loss + 1;

  static const size_t SMEM = 17556 * sizeof(float); // 70224 B -> 2 blocks/CU
  hipFuncSetAttribute(reinterpret_cast<const void*>(k_stage),
                      hipFuncAttributeMaxDynamicSharedMemorySize, (int)SMEM);

  k_prep<<<(QST * KC + PNTH - 1) / PNTH, PNTH, 0, stream>>>(cb, cvec64, cvec32, packB);

  for (int s = 0; s < QST; s++) {
    const float* rin = (s == 0) ? x : r;
    k_stage<<<N_ROWS / BM, NTH, SMEM, stream>>>(s, rin, r, x, cb, cvec64, cvec32,
                                                packB, out_idx, part,
                                                (s == QST - 1) ? 1 : 0);
  }

  k_loss<<<1, PNTH, 0, stream>>>(part, out_loss);
}

// Round 12
// 708.481 us; speedup vs baseline: 1.3304x; 1.0384x over previous
//
#include <hip/hip_runtime.h>

#define N_ROWS 131072
#define DIM    128
#define QST    4
#define KC     1024
#define BM     256     // rows per workgroup (4 waves x 64 rows)
#define NTH    256
#define PNTH   256
#define NWAVE  4
#define NC     32      // 32 codes per chunk, 16 KB fragments
#define EPS    6e-3f   // certified fp16-split argmin margin
#define FLAGB  (1 << 16)

typedef _Float16 h8  __attribute__((ext_vector_type(8)));
typedef float    fx4 __attribute__((ext_vector_type(4)));

typedef __attribute__((address_space(3))) void lds_void;
typedef const __attribute__((address_space(1))) void glb_void;

#define MFMA16(a, b, c) __builtin_amdgcn_mfma_f32_16x16x32_f16((a), (b), (c), 0, 0, 0)

// packB halfs layout: [q][ch(32)][ctl(2)][kt(4)][hl(2)][lane(64)][j(8)]
// -> each 16 KB chunk (32 codes) stages linearly into LDS.
__global__ void k_prep(const float* __restrict__ cb,
                       double* __restrict__ cvec64, float* __restrict__ cvec32,
                       _Float16* __restrict__ packB) {
  int gid = blockIdx.x * blockDim.x + threadIdx.x;
  if (gid >= QST * KC) return;
  int q = gid >> 10, code = gid & (KC - 1);
  int ch = code >> 5, ctl = (code >> 4) & 1, n = code & 15;
  const float* e = cb + ((size_t)q * KC + code) * DIM;
  double s = 0.0;
  for (int d = 0; d < DIM; d++) {
    float v = e[d];
    s = fma((double)v, (double)v, s);
    int kt = d >> 5, g = (d >> 3) & 3, j = d & 7;
    int lane = g * 16 + n;
    size_t base = ((size_t)q * NC + ch) * 8192
                + (size_t)((ctl * 4 + kt) * 2) * 512 + lane * 8 + j;
    _Float16 hh = (_Float16)v;
    packB[base]       = hh;                          // hi
    packB[base + 512] = (_Float16)(v - (float)hh);   // lo
  }
  cvec64[q * KC + code] = s;
  cvec32[q * KC + code] = (float)s;
}

__global__ __launch_bounds__(NTH, 2) void k_stage(
    int st, const float* rin, float* rout, const float* __restrict__ x,
    const float* __restrict__ cb,
    const double* __restrict__ cvec64, const float* __restrict__ cvec32,
    const _Float16* __restrict__ packB,
    float* __restrict__ oidx, float* __restrict__ lpart, int final_stage)
{
  extern __shared__ float smem[];
  _Float16* Bl    = (_Float16*)smem;              // [4][8192] halfs = 64 KB ring
  float*    cvecL = smem + 16384;                 // 1024 floats = 4 KB
  int*      idxs  = (int*)(smem + 17408);         // 256 ints
  double*   redd  = (double*)(smem + 17664);      // 4 doubles (8B aligned)
  int*      redi  = (int*)(smem + 17672);         // 4 ints
  float*    redf  = smem + 17676;                 // 4 floats
  int*      flags = (int*)(smem + 17680);         // 4 ints

  const int tid = threadIdx.x;
  const int lane = tid & 63, wv = tid >> 6;
  const int tx = lane & 15;
  const size_t rowbase = (size_t)blockIdx.x * BM;

  const double*   cq64 = cvec64 + st * KC;
  const float*    cq32 = cvec32 + st * KC;
  const float*    Eq   = cb + (size_t)st * KC * DIM;
  const _Float16* PBq  = packB + (size_t)st * 262144;

  // ---- stage cvec32 into LDS (main-loop score reads must not touch vmcnt)
  for (int i = tid; i < KC; i += NTH) cvecL[i] = cq32[i];

  // ---- A-fragments: 4 rowtiles x 4 ktiles, fp16 hi/lo, straight from global
  h8 ah[4][4], al[4][4];
  #pragma unroll
  for (int rt = 0; rt < 4; rt++) {
    const float* rowp = rin + (rowbase + wv * 64 + rt * 16 + (lane & 15)) * (size_t)DIM
                        + ((lane >> 4) * 8);
    #pragma unroll
    for (int kt = 0; kt < 4; kt++) {
      float4 f0 = *(const float4*)(rowp + kt * 32);
      float4 f1 = *(const float4*)(rowp + kt * 32 + 4);
      float vv[8] = {f0.x, f0.y, f0.z, f0.w, f1.x, f1.y, f1.z, f1.w};
      #pragma unroll
      for (int j = 0; j < 8; j++) {
        _Float16 hh = (_Float16)vv[j];
        ah[rt][kt][j] = hh;
        al[rt][kt][j] = (_Float16)(vv[j] - (float)hh);
      }
    }
  }

  __syncthreads();   // cvecL visible; drains all prologue VMEM (vmcnt->0)

  // stage one 16 KB chunk into ring buf (c&3): per wave 4 x (64 lanes x 16 B)
  auto stageC = [&](int c) {
    const _Float16* src = PBq + (size_t)c * 8192 + wv * 2048 + lane * 8;
    _Float16* dst = Bl + (size_t)(c & 3) * 8192 + wv * 2048;   // wave-uniform base
    #pragma unroll
    for (int i = 0; i < 4; i++)
      __builtin_amdgcn_global_load_lds((glb_void*)(src + i * 512),
                                       (lds_void*)(dst + i * 512), 16, 0, 0);
  };

  float b1[16], b2[16];
  int   i1[16];
  #pragma unroll
  for (int i = 0; i < 16; i++) { b1[i] = 3.4e38f; b2[i] = 3.4e38f; i1[i] = 0; }

  const fx4 zero4 = {0.f, 0.f, 0.f, 0.f};

  // prologue: 3 chunks in flight (12 loads/wave)
  stageC(0); stageC(1); stageC(2);

  #pragma unroll 1
  for (int ch = 0; ch < NC; ch++) {
    // counted wait (T4): chunk ch's 4 loads retired; up to 2 newer in flight
    int rem = NC - 1 - ch;
    if (rem >= 2)      asm volatile("s_waitcnt vmcnt(8)" ::: "memory");
    else if (rem == 1) asm volatile("s_waitcnt vmcnt(4)" ::: "memory");
    else               asm volatile("s_waitcnt vmcnt(0)" ::: "memory");
    __builtin_amdgcn_s_barrier();   // all waves' ch-loads landed; buf (ch-1)&3 retired
    asm volatile("" ::: "memory");  // pin the stage below the barrier
    if (ch + 3 < NC) stageC(ch + 3);
    // ledger: stage writes buf (ch+3)&3 == (ch-1)&3 (consumed pre-barrier);
    // current reads buf ch&3; in-flight ch+1,ch+2 occupy the other two.

    const _Float16* Bb = Bl + (size_t)(ch & 3) * 8192;
    #pragma unroll
    for (int ctl = 0; ctl < 2; ctl++) {
      fx4 acc[4];
      acc[0] = zero4; acc[1] = zero4; acc[2] = zero4; acc[3] = zero4;

      __builtin_amdgcn_s_setprio(1);
      #pragma unroll
      for (int kt = 0; kt < 4; kt++) {
        const _Float16* p = Bb + (size_t)((ctl * 4 + kt) * 2) * 512 + lane * 8;
        h8 bh = *(const h8*)p;
        h8 bl = *(const h8*)(p + 512);
        #pragma unroll
        for (int rt = 0; rt < 4; rt++) {
          acc[rt] = MFMA16(ah[rt][kt], bh, acc[rt]);
          acc[rt] = MFMA16(al[rt][kt], bh, acc[rt]);
          acc[rt] = MFMA16(ah[rt][kt], bl, acc[rt]);
        }
      }
      __builtin_amdgcn_s_setprio(0);

      // ---- scores; per-row top-2. C layout: col=lane&15, row=(lane>>4)*4+reg
      int code = ch * 32 + ctl * 16 + tx;
      float cvv = cvecL[code];
      #pragma unroll
      for (int rt = 0; rt < 4; rt++) {
        #pragma unroll
        for (int j = 0; j < 4; j++) {
          float sc = fmaf(-2.f, acc[rt][j], cvv);
          int r = rt * 4 + j;
          if (sc < b1[r]) { b2[r] = b1[r]; b1[r] = sc; i1[r] = code; }
          else            { b2[r] = fminf(b2[r], sc); }
        }
      }
    }
  }

  // ---- cross-lane top-2 reduce over the 16 lanes sharing each row
  #pragma unroll
  for (int m = 1; m < 16; m <<= 1) {
    #pragma unroll
    for (int r = 0; r < 16; r++) {
      float ob1 = __shfl_xor(b1[r], m, 64);
      int   oi1 = __shfl_xor(i1[r], m, 64);
      float ob2 = __shfl_xor(b2[r], m, 64);
      bool take = (ob1 < b1[r]) || (ob1 == b1[r] && oi1 < i1[r]);
      float loser = take ? b1[r] : ob1;
      if (take) { b1[r] = ob1; i1[r] = oi1; }
      b2[r] = fminf(fminf(b2[r], ob2), loser);
    }
  }

  if (tx == 0) {
    int g = lane >> 4;
    #pragma unroll
    for (int rt = 0; rt < 4; rt++)
      #pragma unroll
      for (int j = 0; j < 4; j++) {
        int r = rt * 4 + j;
        int fl = (b2[r] - b1[r] <= EPS) ? FLAGB : 0;
        idxs[wv * 64 + rt * 16 + g * 4 + j] = i1[r] | fl;
      }
  }
  __syncthreads();

  // ---- exact fp64 rescue for uncertain rows (rare); reads codebook rows
  {
    bool pred = (idxs[tid] & FLAGB) != 0;   // BM == NTH
    unsigned long long bal = __ballot(pred);
    if (lane == 0) flags[wv] = (bal != 0ull) ? 1 : 0;
  }
  __syncthreads();
  int anyflag = flags[0] | flags[1] | flags[2] | flags[3];
  if (anyflag) {
    for (int row = 0; row < BM; row++) {
      if (!(idxs[row] & FLAGB)) continue;          // uniform branch
      const float* rrow = rin + (rowbase + row) * (size_t)DIM;
      double dot[4] = {0.0, 0.0, 0.0, 0.0};
      for (int d = 0; d < DIM; d++) {
        double a = (double)rrow[d];                // broadcast load
        #pragma unroll
        for (int c = 0; c < 4; c++)
          dot[c] = fma(a, (double)Eq[(size_t)(tid + c * NTH) * DIM + d], dot[c]);
      }
      double bs = 1e300; int bk = 0;
      #pragma unroll
      for (int c = 0; c < 4; c++) {
        int k = tid + c * NTH;
        double s = fma(-2.0, dot[c], cq64[k]);
        if (s < bs || (s == bs && k < bk)) { bs = s; bk = k; }
      }
      #pragma unroll
      for (int m = 1; m < 64; m <<= 1) {
        double ob = __shfl_xor(bs, m, 64);
        int    ok = __shfl_xor(bk, m, 64);
        if (ob < bs || (ob == bs && ok < bk)) { bs = ob; bk = ok; }
      }
      if (lane == 0) { redd[wv] = bs; redi[wv] = bk; }
      __syncthreads();
      if (tid == 0) {
        double fb = redd[0]; int fk = redi[0];
        #pragma unroll
        for (int w = 1; w < NWAVE; w++) {
          if (redd[w] < fb || (redd[w] == fb && redi[w] < fk)) { fb = redd[w]; fk = redi[w]; }
        }
        idxs[row] = fk;                            // flag cleared
      }
      __syncthreads();
    }
  }

  // ---- fused epilogue, fully coalesced flat writes:
  //      r_new = r_old - E[idx]; loss += (E[idx]-r_old)^2; last stage: out = x - r_new
  {
    float lsum = 0.f;
    #pragma unroll 1
    for (int it = 0; it < 32; it++) {
      int g = it * NTH + tid;
      int row = g >> 5, c4 = g & 31;
      int kidx = idxs[row] & 1023;
      if ((g & 31) == 0) oidx[(rowbase + row) * 4 + st] = (float)kidx;
      float4 ev = *(const float4*)(Eq + (size_t)kidx * DIM + c4 * 4);
      float4 rv = *(const float4*)(rin + (rowbase + row) * (size_t)DIM + c4 * 4);
      float4 dv = make_float4(rv.x - ev.x, rv.y - ev.y, rv.z - ev.z, rv.w - ev.w);
      lsum = fmaf(dv.x, dv.x, lsum);
      lsum = fmaf(dv.y, dv.y, lsum);
      lsum = fmaf(dv.z, dv.z, lsum);
      lsum = fmaf(dv.w, dv.w, lsum);
      float4 wv4 = dv;
      if (final_stage) {
        float4 xv = *(const float4*)(x + (rowbase + row) * (size_t)DIM + c4 * 4);
        wv4 = make_float4(xv.x - dv.x, xv.y - dv.y, xv.z - dv.z, xv.w - dv.w);
      }
      *(float4*)(rout + (rowbase + row) * (size_t)DIM + c4 * 4) = wv4;
    }
    #pragma unroll
    for (int m = 1; m < 64; m <<= 1) lsum += __shfl_xor(lsum, m, 64);
    if (lane == 0) redf[wv] = lsum;
    __syncthreads();
    if (tid == 0) lpart[st * (N_ROWS / BM) + blockIdx.x] =
        redf[0] + redf[1] + redf[2] + redf[3];
  }
}

__global__ void k_loss(const float* __restrict__ part, float* __restrict__ o) {
  __shared__ float red[4];
  int tid = threadIdx.x;
  float s = 0.f;
  for (int i = tid; i < QST * (N_ROWS / BM); i += PNTH) s += part[i];
  #pragma unroll
  for (int m = 1; m < 64; m <<= 1) s += __shfl_xor(s, m, 64);
  if ((tid & 63) == 0) red[tid >> 6] = s;
  __syncthreads();
  if (tid == 0)
    o[0] = (red[0] + red[1] + red[2] + red[3]) *
           (1.25f / ((float)QST * (float)N_ROWS * (float)DIM));
}

extern "C" void kernel_launch(void* const* d_in, const int* in_sizes, int n_in,
                              void* d_out, int out_size, void* d_ws, size_t ws_size,
                              hipStream_t stream) {
  const float* x  = (const float*)d_in[0];
  const float* cb = (const float*)d_in[1];
  float* out = (float*)d_out;
  float* ws  = (float*)d_ws;

  float*    r      = out;                                   // residual in x_q region
  double*   cvec64 = (double*)ws;                           // Q*K fp64 ||E||^2
  float*    cvec32 = (float*)(cvec64 + (size_t)QST * KC);
  float*    part   = cvec32 + (size_t)QST * KC;             // Q*512 partials
  _Float16* packB  = (_Float16*)(part + (size_t)QST * (N_ROWS / BM)); // 2 MB frags

  float* out_loss = out + (size_t)N_ROWS * DIM;
  float* out_idx  = out_loss + 1;

  static const size_t SMEM = 17684 * sizeof(float); // 70736 B -> 2 blocks/CU
  hipFuncSetAttribute(reinterpret_cast<const void*>(k_stage),
                      hipFuncAttributeMaxDynamicSharedMemorySize, (int)SMEM);

  k_prep<<<(QST * KC + PNTH - 1) / PNTH, PNTH, 0, stream>>>(cb, cvec64, cvec32, packB);

  for (int s = 0; s < QST; s++) {
    const float* rin = (s == 0) ? x : r;
    k_stage<<<N_ROWS / BM, NTH, SMEM, stream>>>(s, rin, r, x, cb, cvec64, cvec32,
                                                packB, out_idx, part,
                                                (s == QST - 1) ? 1 : 0);
  }

  k_loss<<<1, PNTH, 0, stream>>>(part, out_loss);
}

// Round 13
// 641.180 us; speedup vs baseline: 1.4701x; 1.1050x over previous
//
#include <hip/hip_runtime.h>

#define N_ROWS 131072
#define DIM    128
#define QST    4
#define KC     1024
#define BM     128     // rows per workgroup (4 waves x 32 rows)
#define NTH    256
#define PNTH   256
#define NWAVE  4
#define NCHUNK 64      // 16 codes per chunk, 8 KB fragments
#define EPS    6e-3f   // certified fp16-split argmin margin
#define FLAGB  (1 << 16)

typedef _Float16 h8  __attribute__((ext_vector_type(8)));
typedef float    fx4 __attribute__((ext_vector_type(4)));

typedef __attribute__((address_space(3))) void lds_void;
typedef const __attribute__((address_space(1))) void glb_void;

#define MFMA16(a, b, c) __builtin_amdgcn_mfma_f32_16x16x32_f16((a), (b), (c), 0, 0, 0)

// packB halfs layout: [q][ch(64)][kt(4)][hl(2)][lane(64)][j(8)]
// -> each 8 KB chunk (16 codes) stages linearly into LDS.
__global__ void k_prep(const float* __restrict__ cb,
                       double* __restrict__ cvec64, float* __restrict__ cvec32,
                       _Float16* __restrict__ packB) {
  int gid = blockIdx.x * blockDim.x + threadIdx.x;
  if (gid >= QST * KC) return;
  int q = gid >> 10, code = gid & (KC - 1);
  int ch = code >> 4, n = code & 15;
  const float* e = cb + ((size_t)q * KC + code) * DIM;
  double s = 0.0;
  for (int d = 0; d < DIM; d++) {
    float v = e[d];
    s = fma((double)v, (double)v, s);
    int kt = d >> 5, g = (d >> 3) & 3, j = d & 7;
    int lane = g * 16 + n;
    size_t base = ((size_t)q * NCHUNK + ch) * 4096 + (size_t)kt * 1024 + lane * 8 + j;
    _Float16 hh = (_Float16)v;
    packB[base]       = hh;                          // hi
    packB[base + 512] = (_Float16)(v - (float)hh);   // lo
  }
  cvec64[q * KC + code] = s;
  cvec32[q * KC + code] = (float)s;
}

__global__ __launch_bounds__(NTH, 4) void k_stage(
    int st, const float* rin, float* rout, const float* __restrict__ x,
    const float* __restrict__ cb,
    const double* __restrict__ cvec64, const float* __restrict__ cvec32,
    const _Float16* __restrict__ packB,
    float* __restrict__ oidx, float* __restrict__ lpart, int final_stage)
{
  extern __shared__ float smem[];
  _Float16* Bl    = (_Float16*)smem;              // [3][4096] halfs = 24 KB ring
  float*    cvecL = smem + 6144;                  // 1024 floats = 4 KB
  int*      idxs  = (int*)(smem + 7168);          // 128 ints
  double*   redd  = (double*)(smem + 7296);       // 4 doubles (8B aligned)
  int*      redi  = (int*)(smem + 7304);          // 4 ints
  float*    redf  = smem + 7308;                  // 4 floats
  int*      flags = (int*)(smem + 7312);          // 4 ints

  const int tid = threadIdx.x;
  const int lane = tid & 63, wv = tid >> 6;
  const int tx = lane & 15;
  const size_t rowbase = (size_t)blockIdx.x * BM;

  const double*   cq64 = cvec64 + st * KC;
  const float*    cq32 = cvec32 + st * KC;
  const float*    Eq   = cb + (size_t)st * KC * DIM;
  const _Float16* PBq  = packB + (size_t)st * 262144;

  // ---- stage cvec32 into LDS (main-loop score reads must not touch vmcnt)
  for (int i = tid; i < KC; i += NTH) cvecL[i] = cq32[i];

  // ---- A-fragments: 2 rowtiles x 4 ktiles, fp16 hi/lo, straight from global
  h8 ah[2][4], al[2][4];
  #pragma unroll
  for (int rt = 0; rt < 2; rt++) {
    const float* rowp = rin + (rowbase + wv * 32 + rt * 16 + (lane & 15)) * (size_t)DIM
                        + ((lane >> 4) * 8);
    #pragma unroll
    for (int kt = 0; kt < 4; kt++) {
      float4 f0 = *(const float4*)(rowp + kt * 32);
      float4 f1 = *(const float4*)(rowp + kt * 32 + 4);
      float vv[8] = {f0.x, f0.y, f0.z, f0.w, f1.x, f1.y, f1.z, f1.w};
      #pragma unroll
      for (int j = 0; j < 8; j++) {
        _Float16 hh = (_Float16)vv[j];
        ah[rt][kt][j] = hh;
        al[rt][kt][j] = (_Float16)(vv[j] - (float)hh);
      }
    }
  }

  __syncthreads();   // cvecL visible; drains all prologue VMEM (vmcnt->0)

  // stage one 8 KB chunk into ring buf: per wave 2 x (64 lanes x 16 B)
  auto stageB = [&](int ch, int buf) {
    const _Float16* src = PBq + (size_t)ch * 4096 + wv * 1024 + lane * 8;
    _Float16* dst = Bl + (size_t)buf * 4096 + wv * 1024;   // wave-uniform base
    #pragma unroll
    for (int i = 0; i < 2; i++)
      __builtin_amdgcn_global_load_lds((glb_void*)(src + i * 512),
                                       (lds_void*)(dst + i * 512), 16, 0, 0);
  };

  float b1[8], b2[8];
  int   i1[8];
  #pragma unroll
  for (int i = 0; i < 8; i++) { b1[i] = 3.4e38f; b2[i] = 3.4e38f; i1[i] = 0; }

  const fx4 zero4 = {0.f, 0.f, 0.f, 0.f};
  fx4 accPrev[2];
  accPrev[0] = zero4; accPrev[1] = zero4;

  // prologue: fill ring 2 deep (4 loads in flight per wave)
  stageB(0, 0); stageB(1, 1);

  int buf = 0, bufStage = 2;   // buf = ch%3, bufStage = (ch+2)%3
  #pragma unroll 1
  for (int ch = 0; ch < NCHUNK; ch++) {
    // counted per-wave wait (T4): chunk ch's 2 loads are the oldest of <=4 in
    // flight -> vmcnt(2) retires them; chunk ch+1's stay in flight.
    if (ch < NCHUNK - 1) asm volatile("s_waitcnt vmcnt(2)" ::: "memory");
    else                 asm volatile("s_waitcnt vmcnt(0)" ::: "memory");
    __builtin_amdgcn_s_barrier();       // all waves' ch-loads visible; buf (ch-1)%3 retired
    asm volatile("" ::: "memory");      // pin the stage below the barrier
    if (ch + 2 < NCHUNK) stageB(ch + 2, bufStage);
    // ledger: stage writes buf (ch+2)%3 == (ch-1)%3, whose ds_reads all retired
    // before iter ch-1's MFMAs (lgkm), hence before this barrier. deferred score
    // reads only registers -> no LDS hazard.

    // ---- deferred score of chunk ch-1 (register-only; independent of MFMAs
    //      below -> scheduler interleaves VALU with MFMA issue)
    if (ch > 0) {
      int code = (ch - 1) * 16 + tx;
      float cvv = cvecL[code];
      #pragma unroll
      for (int rt = 0; rt < 2; rt++) {
        #pragma unroll
        for (int j = 0; j < 4; j++) {
          float sc = fmaf(-2.f, accPrev[rt][j], cvv);
          int r = rt * 4 + j;
          if (sc < b1[r]) { b2[r] = b1[r]; b1[r] = sc; i1[r] = code; }
          else            { b2[r] = fminf(b2[r], sc); }
        }
      }
    }

    // ---- MFMA chunk ch
    const _Float16* Bb = Bl + (size_t)buf * 4096;
    fx4 acc[2];
    acc[0] = zero4; acc[1] = zero4;

    __builtin_amdgcn_s_setprio(1);
    #pragma unroll
    for (int kt = 0; kt < 4; kt++) {
      const _Float16* p = Bb + (size_t)kt * 1024 + lane * 8;
      h8 bh = *(const h8*)p;
      h8 bl = *(const h8*)(p + 512);
      #pragma unroll
      for (int rt = 0; rt < 2; rt++) {
        acc[rt] = MFMA16(ah[rt][kt], bh, acc[rt]);
        acc[rt] = MFMA16(al[rt][kt], bh, acc[rt]);
        acc[rt] = MFMA16(ah[rt][kt], bl, acc[rt]);
      }
    }
    __builtin_amdgcn_s_setprio(0);

    accPrev[0] = acc[0];
    accPrev[1] = acc[1];

    buf = (buf == 2) ? 0 : buf + 1;
    bufStage = (bufStage == 2) ? 0 : bufStage + 1;
  }

  // ---- tail: score the final chunk
  {
    int code = (NCHUNK - 1) * 16 + tx;
    float cvv = cvecL[code];
    #pragma unroll
    for (int rt = 0; rt < 2; rt++) {
      #pragma unroll
      for (int j = 0; j < 4; j++) {
        float sc = fmaf(-2.f, accPrev[rt][j], cvv);
        int r = rt * 4 + j;
        if (sc < b1[r]) { b2[r] = b1[r]; b1[r] = sc; i1[r] = code; }
        else            { b2[r] = fminf(b2[r], sc); }
      }
    }
  }

  // ---- cross-lane top-2 reduce over the 16 lanes sharing each row
  #pragma unroll
  for (int m = 1; m < 16; m <<= 1) {
    #pragma unroll
    for (int r = 0; r < 8; r++) {
      float ob1 = __shfl_xor(b1[r], m, 64);
      int   oi1 = __shfl_xor(i1[r], m, 64);
      float ob2 = __shfl_xor(b2[r], m, 64);
      bool take = (ob1 < b1[r]) || (ob1 == b1[r] && oi1 < i1[r]);
      float loser = take ? b1[r] : ob1;
      if (take) { b1[r] = ob1; i1[r] = oi1; }
      b2[r] = fminf(fminf(b2[r], ob2), loser);
    }
  }

  if (tx == 0) {
    int g = lane >> 4;
    #pragma unroll
    for (int rt = 0; rt < 2; rt++)
      #pragma unroll
      for (int j = 0; j < 4; j++) {
        int r = rt * 4 + j;
        int fl = (b2[r] - b1[r] <= EPS) ? FLAGB : 0;
        idxs[wv * 32 + rt * 16 + g * 4 + j] = i1[r] | fl;
      }
  }
  __syncthreads();

  // ---- exact fp64 rescue for uncertain rows (rare); reads codebook rows
  {
    bool pred = (tid < BM) && (idxs[tid] & FLAGB);
    unsigned long long bal = __ballot(pred);
    if (lane == 0) flags[wv] = (bal != 0ull) ? 1 : 0;
  }
  __syncthreads();
  int anyflag = flags[0] | flags[1] | flags[2] | flags[3];
  if (anyflag) {
    for (int row = 0; row < BM; row++) {
      if (!(idxs[row] & FLAGB)) continue;          // uniform branch
      const float* rrow = rin + (rowbase + row) * (size_t)DIM;
      double dot[4] = {0.0, 0.0, 0.0, 0.0};
      for (int d = 0; d < DIM; d++) {
        double a = (double)rrow[d];                // broadcast load
        #pragma unroll
        for (int c = 0; c < 4; c++)
          dot[c] = fma(a, (double)Eq[(size_t)(tid + c * NTH) * DIM + d], dot[c]);
      }
      double bs = 1e300; int bk = 0;
      #pragma unroll
      for (int c = 0; c < 4; c++) {
        int k = tid + c * NTH;
        double s = fma(-2.0, dot[c], cq64[k]);
        if (s < bs || (s == bs && k < bk)) { bs = s; bk = k; }
      }
      #pragma unroll
      for (int m = 1; m < 64; m <<= 1) {
        double ob = __shfl_xor(bs, m, 64);
        int    ok = __shfl_xor(bk, m, 64);
        if (ob < bs || (ob == bs && ok < bk)) { bs = ob; bk = ok; }
      }
      if (lane == 0) { redd[wv] = bs; redi[wv] = bk; }
      __syncthreads();
      if (tid == 0) {
        double fb = redd[0]; int fk = redi[0];
        #pragma unroll
        for (int w = 1; w < NWAVE; w++) {
          if (redd[w] < fb || (redd[w] == fb && redi[w] < fk)) { fb = redd[w]; fk = redi[w]; }
        }
        idxs[row] = fk;                            // flag cleared
      }
      __syncthreads();
    }
  }

  // ---- fused epilogue, fully coalesced flat writes:
  //      r_new = r_old - E[idx]; loss += (E[idx]-r_old)^2; last stage: out = x - r_new
  {
    float lsum = 0.f;
    #pragma unroll 1
    for (int it = 0; it < 16; it++) {
      int g = it * NTH + tid;
      int row = g >> 5, c4 = g & 31;
      int kidx = idxs[row] & 1023;
      if ((g & 31) == 0) oidx[(rowbase + row) * 4 + st] = (float)kidx;
      float4 ev = *(const float4*)(Eq + (size_t)kidx * DIM + c4 * 4);
      float4 rv = *(const float4*)(rin + (rowbase + row) * (size_t)DIM + c4 * 4);
      float4 dv = make_float4(rv.x - ev.x, rv.y - ev.y, rv.z - ev.z, rv.w - ev.w);
      lsum = fmaf(dv.x, dv.x, lsum);
      lsum = fmaf(dv.y, dv.y, lsum);
      lsum = fmaf(dv.z, dv.z, lsum);
      lsum = fmaf(dv.w, dv.w, lsum);
      float4 wv4 = dv;
      if (final_stage) {
        float4 xv = *(const float4*)(x + (rowbase + row) * (size_t)DIM + c4 * 4);
        wv4 = make_float4(xv.x - dv.x, xv.y - dv.y, xv.z - dv.z, xv.w - dv.w);
      }
      *(float4*)(rout + (rowbase + row) * (size_t)DIM + c4 * 4) = wv4;
    }
    #pragma unroll
    for (int m = 1; m < 64; m <<= 1) lsum += __shfl_xor(lsum, m, 64);
    if (lane == 0) redf[wv] = lsum;
    __syncthreads();
    if (tid == 0) lpart[st * (N_ROWS / BM) + blockIdx.x] =
        redf[0] + redf[1] + redf[2] + redf[3];
  }
}

__global__ void k_loss(const float* __restrict__ part, float* __restrict__ o) {
  __shared__ float red[4];
  int tid = threadIdx.x;
  float s = 0.f;
  for (int i = tid; i < QST * (N_ROWS / BM); i += PNTH) s += part[i];
  #pragma unroll
  for (int m = 1; m < 64; m <<= 1) s += __shfl_xor(s, m, 64);
  if ((tid & 63) == 0) red[tid >> 6] = s;
  __syncthreads();
  if (tid == 0)
    o[0] = (red[0] + red[1] + red[2] + red[3]) *
           (1.25f / ((float)QST * (float)N_ROWS * (float)DIM));
}

extern "C" void kernel_launch(void* const* d_in, const int* in_sizes, int n_in,
                              void* d_out, int out_size, void* d_ws, size_t ws_size,
                              hipStream_t stream) {
  const float* x  = (const float*)d_in[0];
  const float* cb = (const float*)d_in[1];
  float* out = (float*)d_out;
  float* ws  = (float*)d_ws;

  float*    r      = out;                                   // residual in x_q region
  double*   cvec64 = (double*)ws;                           // Q*K fp64 ||E||^2
  float*    cvec32 = (float*)(cvec64 + (size_t)QST * KC);
  float*    part   = cvec32 + (size_t)QST * KC;             // Q*1024 partials
  _Float16* packB  = (_Float16*)(part + (size_t)QST * (N_ROWS / BM)); // 2 MB frags

  float* out_loss = out + (size_t)N_ROWS * DIM;
  float* out_idx  = out_loss + 1;

  static const size_t SMEM = 7316 * sizeof(float); // 29264 B -> 4 blocks/CU
  hipFuncSetAttribute(reinterpret_cast<const void*>(k_stage),
                      hipFuncAttributeMaxDynamicSharedMemorySize, (int)SMEM);

  k_prep<<<(QST * KC + PNTH - 1) / PNTH, PNTH, 0, stream>>>(cb, cvec64, cvec32, packB);

  for (int s = 0; s < QST; s++) {
    const float* rin = (s == 0) ? x : r;
    k_stage<<<N_ROWS / BM, NTH, SMEM, stream>>>(s, rin, r, x, cb, cvec64, cvec32,
                                                packB, out_idx, part,
                                                (s == QST - 1) ? 1 : 0);
  }

  k_loss<<<1, PNTH, 0, stream>>>(part, out_loss);
}